// Round 1
// baseline (380.217 us; speedup 1.0000x reference)
//
#include <hip/hip_runtime.h>
#include <hip/hip_fp16.h>
#include <cstdint>
#include <cstddef>

typedef _Float16 f16;
typedef __attribute__((ext_vector_type(4))) _Float16 f16x4;
typedef __attribute__((ext_vector_type(8))) _Float16 f16x8;
typedef __attribute__((ext_vector_type(4))) float f32x4;

#define C_INV_SQRT2 0.70710678118654752440f

__device__ __forceinline__ void gld_lds16(const void* g, void* l) {
  __builtin_amdgcn_global_load_lds((const __attribute__((address_space(1))) void*)g,
                                   (__attribute__((address_space(3))) void*)l, 16, 0, 0);
}

// ---------------- conversion kernels ----------------
__global__ __launch_bounds__(256) void cvt_f32_f16_k(const float* __restrict__ in,
                                                     f16* __restrict__ out, int n4) {
  int i = blockIdx.x * 256 + threadIdx.x;
  if (i >= n4) return;
  const float4 x = ((const float4*)in)[i];
  f16x4 y;
  y.x = (f16)x.x; y.y = (f16)x.y; y.z = (f16)x.z; y.w = (f16)x.w;
  ((f16x4*)out)[i] = y;
}

// pack W_qkv rows {0..1023} and {2048..3071} into Wo[2048][1024] f16; same for bias
__global__ __launch_bounds__(256) void pack_wqv_k(const float* __restrict__ W,
                                                  const float* __restrict__ b,
                                                  f16* __restrict__ Wo,
                                                  float* __restrict__ bo) {
  int i = blockIdx.x * 256 + threadIdx.x;  // 0 .. 2048*256-1 (float4 granularity)
  int n = i >> 8;
  int c = (i & 255) * 4;
  int sn = (n < 1024) ? n : (n + 1024);
  const float4 x = *(const float4*)(W + (size_t)sn * 1024 + c);
  f16x4 y; y.x = (f16)x.x; y.y = (f16)x.y; y.z = (f16)x.z; y.w = (f16)x.w;
  *(f16x4*)(Wo + (size_t)n * 1024 + c) = y;
  if (i < 2048) bo[i] = b[(i < 1024) ? i : (i + 1024)];
}

// ---------------- GEMM: C[M,N] = A[M,K] * B[N,K]^T + bias[N] ----------------
// 128x128 tile, BK=32, 256 threads = 4 waves (2x2), per-wave 64x64 (4x4 frags of 16x16x32 f16)
template <typename CT>
__global__ __launch_bounds__(256) void gemm_bt_k(const f16* __restrict__ A,
                                                 const f16* __restrict__ B,
                                                 const float* __restrict__ bias,
                                                 CT* __restrict__ C,
                                                 int M, int N, int K) {
  __shared__ f16 As[128 * 32];
  __shared__ f16 Bs[128 * 32];
  const int t = threadIdx.x;
  const int w = t >> 6;
  const int l = t & 63;
  const int wm = w >> 1;  // 0..1
  const int wn = w & 1;   // 0..1
  const int m0 = blockIdx.y * 128;
  const int n0 = blockIdx.x * 128;

  // staging: thread t covers 16B chunk at linear f16 offset t*8 of a [64][32] half-tile
  const int srow = t >> 2;        // 0..63
  const int scol = (t & 3) * 8;   // f16 offset in row
  const f16* gA = A + (size_t)(m0 + srow) * K + scol;
  const f16* gB = B + (size_t)(n0 + srow) * K + scol;
  f16* lAw = As + w * 512;  // wave-uniform LDS base (64 lanes * 8 f16)
  f16* lBw = Bs + w * 512;

  const int lrow = l & 15;
  const int kch = l >> 4;  // 0..3
  const f16* pA = As + (wm * 64 + lrow) * 32 + kch * 8;
  const f16* pB = Bs + (wn * 64 + lrow) * 32 + kch * 8;

  f32x4 acc[4][4] = {};

  for (int k0 = 0; k0 < K; k0 += 32) {
    __syncthreads();
    gld_lds16(gA, lAw);
    gld_lds16(gA + (size_t)64 * K, lAw + 64 * 32);
    gld_lds16(gB, lBw);
    gld_lds16(gB + (size_t)64 * K, lBw + 64 * 32);
    gA += 32;
    gB += 32;
    __syncthreads();
    f16x8 af[4], bf[4];
#pragma unroll
    for (int i = 0; i < 4; i++) af[i] = *(const f16x8*)(pA + i * 16 * 32);
#pragma unroll
    for (int i = 0; i < 4; i++) bf[i] = *(const f16x8*)(pB + i * 16 * 32);
#pragma unroll
    for (int mi = 0; mi < 4; mi++)
#pragma unroll
      for (int ni = 0; ni < 4; ni++)
        acc[mi][ni] =
            __builtin_amdgcn_mfma_f32_16x16x32_f16(af[mi], bf[ni], acc[mi][ni], 0, 0, 0);
  }

  // epilogue: C/D layout col=lane&15, row=(lane>>4)*4+reg
  const int rbase = m0 + wm * 64 + kch * 4;
  const int cbase = n0 + wn * 64 + lrow;
#pragma unroll
  for (int mi = 0; mi < 4; mi++) {
#pragma unroll
    for (int ni = 0; ni < 4; ni++) {
      const int col = cbase + ni * 16;
      const float bb = bias[col];
#pragma unroll
      for (int r = 0; r < 4; r++) {
        const int row = rbase + mi * 16 + r;
        C[(size_t)row * N + col] = (CT)(acc[mi][ni][r] + bb);
      }
    }
  }
}

// ---------------- fused wavelet middle ----------------
// qv: [32768][2048] f16 (cols 0..1023 = q, 1024..2047 = v), out: [32768][1024] f16
// For each (row-group of 8, d): Haar wavedec(3) of q,v; weighted products; idwt(3).
__global__ __launch_bounds__(256) void dwt_middle_k(const f16* __restrict__ qv,
                                                    const float* __restrict__ wq,
                                                    const float* __restrict__ wv,
                                                    f16* __restrict__ out) {
  const int idx = blockIdx.x * 256 + threadIdx.x;  // 0 .. 4096*1024-1
  const int d = idx & 1023;
  const int g = idx >> 10;
  const size_t m0 = (size_t)g * 8;
  const int h = d >> 6, dh = d & 63;

  float q[8], v[8];
#pragma unroll
  for (int i = 0; i < 8; i++) {
    q[i] = (float)qv[(m0 + i) * 2048 + d];
    v[i] = (float)qv[(m0 + i) * 2048 + 1024 + d];
  }
  const float c = C_INV_SQRT2;
  // forward Haar, 3 levels
  float qa1[4], qd1[4], va1[4], vd1[4];
#pragma unroll
  for (int i = 0; i < 4; i++) {
    qd1[i] = (q[2 * i] - q[2 * i + 1]) * c;
    qa1[i] = (q[2 * i] + q[2 * i + 1]) * c;
    vd1[i] = (v[2 * i] - v[2 * i + 1]) * c;
    va1[i] = (v[2 * i] + v[2 * i + 1]) * c;
  }
  float qa2[2], qd2[2], va2[2], vd2[2];
#pragma unroll
  for (int j = 0; j < 2; j++) {
    qd2[j] = (qa1[2 * j] - qa1[2 * j + 1]) * c;
    qa2[j] = (qa1[2 * j] + qa1[2 * j + 1]) * c;
    vd2[j] = (va1[2 * j] - va1[2 * j + 1]) * c;
    va2[j] = (va1[2 * j] + va1[2 * j + 1]) * c;
  }
  const float qd3 = (qa2[0] - qa2[1]) * c, qa3 = (qa2[0] + qa2[1]) * c;
  const float vd3 = (va2[0] - va2[1]) * c, va3 = (va2[0] + va2[1]) * c;

  // weights: weight_[q|v][h][j][dh], j=0 -> cA3, j=1 -> cD3, j=2 -> cD2
  const int wb = h * 192 + dh;
  const float wq0 = wq[wb], wq1 = wq[wb + 64], wq2 = wq[wb + 128];
  const float wv0 = wv[wb], wv1 = wv[wb + 64], wv2 = wv[wb + 128];

  const float pa = (qa3 * wq0) * (va3 * wv0);
  const float pd3 = (qd3 * wq1) * (vd3 * wv1);
  float pd2[2], pd1[4];
#pragma unroll
  for (int j = 0; j < 2; j++) pd2[j] = (qd2[j] * wq2) * (vd2[j] * wv2);
#pragma unroll
  for (int i = 0; i < 4; i++) pd1[i] = qd1[i] * vd1[i];

  // inverse Haar, 3 levels
  float s2[2], s1[4], a8[8];
  s2[0] = (pa + pd3) * c;
  s2[1] = (pa - pd3) * c;
#pragma unroll
  for (int j = 0; j < 2; j++) {
    s1[2 * j] = (s2[j] + pd2[j]) * c;
    s1[2 * j + 1] = (s2[j] - pd2[j]) * c;
  }
#pragma unroll
  for (int i = 0; i < 4; i++) {
    a8[2 * i] = (s1[i] + pd1[i]) * c;
    a8[2 * i + 1] = (s1[i] - pd1[i]) * c;
  }
#pragma unroll
  for (int i = 0; i < 8; i++) out[(m0 + i) * 1024 + d] = (f16)a8[i];
}

// ---------------- launch ----------------
extern "C" void kernel_launch(void* const* d_in, const int* in_sizes, int n_in,
                              void* d_out, int out_size, void* d_ws, size_t ws_size,
                              hipStream_t stream) {
  (void)in_sizes; (void)n_in; (void)out_size; (void)ws_size;
  const float* query = (const float*)d_in[0];
  const float* W_qkv = (const float*)d_in[1];
  const float* b_qkv = (const float*)d_in[2];
  const float* W_out = (const float*)d_in[3];
  const float* b_out = (const float*)d_in[4];
  const float* wq = (const float*)d_in[5];
  const float* wv = (const float*)d_in[6];
  float* out = (float*)d_out;

  // workspace layout
  char* ws = (char*)d_ws;
  f16* qf16 = (f16*)ws;                           // 67,108,864 B (reused as a_f16)
  f16* Wqv = (f16*)(ws + 67108864);               //  4,194,304 B
  float* bqv = (float*)(ws + 67108864 + 4194304); //      8,192 B
  f16* Wout = (f16*)(ws + 67108864 + 4194304 + 8192);  // 2,097,152 B
  // qv intermediate lives in d_out (exactly 32768*2048*2 = out bytes)
  f16* qv = (f16*)d_out;
  f16* a_f16 = qf16;  // alias: qf16 dead after GEMM1

  // 1. query -> f16  (33,554,432 elems = 8,388,608 float4)
  cvt_f32_f16_k<<<dim3(8388608 / 256), dim3(256), 0, stream>>>(query, qf16, 8388608);
  // 2. pack W_qv + bias
  pack_wqv_k<<<dim3(2048), dim3(256), 0, stream>>>(W_qkv, b_qkv, Wqv, bqv);
  // 3. W_out -> f16 (1,048,576 elems = 262,144 float4)
  cvt_f32_f16_k<<<dim3(262144 / 256), dim3(256), 0, stream>>>(W_out, Wout, 262144);
  // 4. GEMM1: qv[32768,2048] = query_f16 * Wqv^T + bqv
  gemm_bt_k<f16><<<dim3(2048 / 128, 32768 / 128), dim3(256), 0, stream>>>(
      qf16, Wqv, bqv, qv, 32768, 2048, 1024);
  // 5. fused wavelet middle: a[32768,1024] f16
  dwt_middle_k<<<dim3(16384), dim3(256), 0, stream>>>(qv, wq, wv, a_f16);
  // 6. GEMM2: out = a * Wout^T + b_out (fp32)
  gemm_bt_k<float><<<dim3(1024 / 128, 32768 / 128), dim3(256), 0, stream>>>(
      a_f16, Wout, b_out, out, 32768, 1024, 1024);
}

// Round 2
// 290.943 us; speedup vs baseline: 1.3068x; 1.3068x over previous
//
#include <hip/hip_runtime.h>
#include <hip/hip_fp16.h>
#include <cstdint>
#include <cstddef>

typedef _Float16 f16;
typedef __attribute__((ext_vector_type(4))) _Float16 f16x4;
typedef __attribute__((ext_vector_type(8))) _Float16 f16x8;
typedef __attribute__((ext_vector_type(4))) float f32x4;

#define C_INV_SQRT2 0.70710678118654752440f

__device__ __forceinline__ void gld_lds16(const void* g, void* l) {
  __builtin_amdgcn_global_load_lds((const __attribute__((address_space(1))) void*)g,
                                   (__attribute__((address_space(3))) void*)l, 16, 0, 0);
}

// ---------------- conversion kernels ----------------
__global__ __launch_bounds__(256) void cvt_f32_f16_k(const float* __restrict__ in,
                                                     f16* __restrict__ out, int n4) {
  int i = blockIdx.x * 256 + threadIdx.x;
  if (i >= n4) return;
  const float4 x = ((const float4*)in)[i];
  f16x4 y;
  y.x = (f16)x.x; y.y = (f16)x.y; y.z = (f16)x.z; y.w = (f16)x.w;
  ((f16x4*)out)[i] = y;
}

// pack W_qkv rows {0..1023} and {2048..3071} into Wo[2048][1024] f16; same for bias
__global__ __launch_bounds__(256) void pack_wqv_k(const float* __restrict__ W,
                                                  const float* __restrict__ b,
                                                  f16* __restrict__ Wo,
                                                  float* __restrict__ bo) {
  int i = blockIdx.x * 256 + threadIdx.x;  // 0 .. 2048*256-1 (float4 granularity)
  int n = i >> 8;
  int c = (i & 255) * 4;
  int sn = (n < 1024) ? n : (n + 1024);
  const float4 x = *(const float4*)(W + (size_t)sn * 1024 + c);
  f16x4 y; y.x = (f16)x.x; y.y = (f16)x.y; y.z = (f16)x.z; y.w = (f16)x.w;
  *(f16x4*)(Wo + (size_t)n * 1024 + c) = y;
  if (i < 2048) bo[i] = b[(i < 1024) ? i : (i + 1024)];
}

// ---------------- 256x256 deep-pipelined GEMM: C[M,N] = A[M,K]*B[N,K]^T + bias[N] ----
// 512 threads = 8 waves (WARPS_M=4 x WARPS_N=2); per-wave 64(M) x 128(N).
// BK=64, double-buffered LDS (128 KiB). Counted vmcnt(8): next tile's 8
// global_load_lds stay in flight across this tile's compute (T3+T4).
// LDS chunk-XOR swizzle (T2, both-sides: inverse-swizzled global src + swizzled read).
// T5 setprio around MFMA clusters. T1 bijective XCD swizzle (nwg % 8 == 0).

#define STAGE(bufidx, k0)                                                          \
  {                                                                                \
    f16* LA = &lds[bufidx][0][0];                                                  \
    f16* LB = &lds[bufidx][1][0];                                                  \
    _Pragma("unroll") for (int i = 0; i < 4; i++) {                                \
      const int u = i * 512 + t;                                                   \
      const int row = u >> 3;                                                      \
      const int col = ((u & 7) ^ (row & 7)) << 3;                                  \
      gld_lds16(GA + (size_t)row * K + (k0) + col, LA + (i * 512 + (w << 6)) * 8); \
    }                                                                              \
    _Pragma("unroll") for (int i = 0; i < 4; i++) {                                \
      const int u = i * 512 + t;                                                   \
      const int row = u >> 3;                                                      \
      const int col = ((u & 7) ^ (row & 7)) << 3;                                  \
      gld_lds16(GB + (size_t)row * K + (k0) + col, LB + (i * 512 + (w << 6)) * 8); \
    }                                                                              \
  }

#define COMPUTE(bufidx)                                                            \
  {                                                                                \
    const f16* As_ = &lds[bufidx][0][0];                                           \
    const f16* Bs_ = &lds[bufidx][1][0];                                           \
    const f16* pA0 = As_ + wm * 4096 + lb0;                                        \
    const f16* pA1 = As_ + wm * 4096 + lb1;                                        \
    const f16* pB0 = Bs_ + wn * 8192 + lb0;                                        \
    const f16* pB1 = Bs_ + wn * 8192 + lb1;                                        \
    f16x8 af[4][2];                                                                \
    _Pragma("unroll") for (int mi = 0; mi < 4; mi++) {                             \
      af[mi][0] = *(const f16x8*)(pA0 + mi * 1024);                                \
      af[mi][1] = *(const f16x8*)(pA1 + mi * 1024);                                \
    }                                                                              \
    _Pragma("unroll") for (int nh = 0; nh < 2; nh++) {                             \
      f16x8 bf[4][2];                                                              \
      _Pragma("unroll") for (int nj = 0; nj < 4; nj++) {                           \
        bf[nj][0] = *(const f16x8*)(pB0 + (nh * 4 + nj) * 1024);                   \
        bf[nj][1] = *(const f16x8*)(pB1 + (nh * 4 + nj) * 1024);                   \
      }                                                                            \
      __builtin_amdgcn_s_setprio(1);                                               \
      _Pragma("unroll") for (int mi = 0; mi < 4; mi++)                             \
        _Pragma("unroll") for (int nj = 0; nj < 4; nj++) {                         \
          acc[mi][nh * 4 + nj] = __builtin_amdgcn_mfma_f32_16x16x32_f16(           \
              af[mi][0], bf[nj][0], acc[mi][nh * 4 + nj], 0, 0, 0);                \
          acc[mi][nh * 4 + nj] = __builtin_amdgcn_mfma_f32_16x16x32_f16(           \
              af[mi][1], bf[nj][1], acc[mi][nh * 4 + nj], 0, 0, 0);                \
        }                                                                          \
      __builtin_amdgcn_s_setprio(0);                                               \
    }                                                                              \
  }

template <typename CT>
__global__ __launch_bounds__(512, 2) void gemm256_k(const f16* __restrict__ A,
                                                    const f16* __restrict__ B,
                                                    const float* __restrict__ bias,
                                                    CT* __restrict__ C,
                                                    int M, int N, int K, int nbx) {
  __shared__ f16 lds[2][2][256 * 64];  // [dbuf][A/B][256 rows x 64 cols] = 128 KiB
  const int t = threadIdx.x;
  const int w = t >> 6, l = t & 63;
  const int wm = w >> 1, wn = w & 1;   // 4 x 2 wave grid
  const int hi = l >> 4, lo = l & 15;

  // T1: bijective XCD swizzle (nwg % 8 == 0 guaranteed by launch)
  const int nwg = gridDim.x;
  const int cpx = nwg >> 3;
  const int bid = blockIdx.x;
  const int nid = (bid & 7) * cpx + (bid >> 3);
  const int by = nid / nbx, bx = nid - by * nbx;
  const int m0 = by * 256, n0 = bx * 256;

  const f16* GA = A + (size_t)m0 * K;
  const f16* GB = B + (size_t)n0 * K;

  // read-side per-lane LDS offsets (f16 units); chunk = ks*4 + hi, swz: ^ (row&7) = ^(l&7)
  const int lb0 = lo * 64 + ((hi ^ (l & 7)) << 3);
  const int lb1 = lo * 64 + (((4 | hi) ^ (l & 7)) << 3);

  f32x4 acc[4][8] = {};
  const int NT = K >> 6;

  STAGE(0, 0);
  for (int tt = 0; tt < NT - 1; ++tt) {
    const int cur = tt & 1;
    STAGE(cur ^ 1, (tt + 1) << 6);                  // prefetch next tile
    asm volatile("s_waitcnt vmcnt(8)" ::: "memory");  // this tile's 8 loads done
    __builtin_amdgcn_s_barrier();
    __builtin_amdgcn_sched_barrier(0);
    COMPUTE(cur);
    __builtin_amdgcn_sched_barrier(0);
    __builtin_amdgcn_s_barrier();                   // all waves done reading buf[cur]
  }
  asm volatile("s_waitcnt vmcnt(0)" ::: "memory");
  __builtin_amdgcn_s_barrier();
  __builtin_amdgcn_sched_barrier(0);
  COMPUTE((NT - 1) & 1);

  // epilogue: C/D layout col = lane&15, row = (lane>>4)*4 + reg
#pragma unroll
  for (int mi = 0; mi < 4; mi++) {
#pragma unroll
    for (int nj = 0; nj < 8; nj++) {
      const int col = n0 + wn * 128 + nj * 16 + lo;
      const float bb = bias[col];
      const size_t base = (size_t)(m0 + wm * 64 + mi * 16 + hi * 4) * N + col;
#pragma unroll
      for (int r = 0; r < 4; r++) C[base + (size_t)r * N] = (CT)(acc[mi][nj][r] + bb);
    }
  }
}

// ---------------- fused wavelet middle ----------------
__global__ __launch_bounds__(256) void dwt_middle_k(const f16* __restrict__ qv,
                                                    const float* __restrict__ wq,
                                                    const float* __restrict__ wv,
                                                    f16* __restrict__ out) {
  const int idx = blockIdx.x * 256 + threadIdx.x;  // 0 .. 4096*1024-1
  const int d = idx & 1023;
  const int g = idx >> 10;
  const size_t m0 = (size_t)g * 8;
  const int h = d >> 6, dh = d & 63;

  float q[8], v[8];
#pragma unroll
  for (int i = 0; i < 8; i++) {
    q[i] = (float)qv[(m0 + i) * 2048 + d];
    v[i] = (float)qv[(m0 + i) * 2048 + 1024 + d];
  }
  const float c = C_INV_SQRT2;
  float qa1[4], qd1[4], va1[4], vd1[4];
#pragma unroll
  for (int i = 0; i < 4; i++) {
    qd1[i] = (q[2 * i] - q[2 * i + 1]) * c;
    qa1[i] = (q[2 * i] + q[2 * i + 1]) * c;
    vd1[i] = (v[2 * i] - v[2 * i + 1]) * c;
    va1[i] = (v[2 * i] + v[2 * i + 1]) * c;
  }
  float qa2[2], qd2[2], va2[2], vd2[2];
#pragma unroll
  for (int j = 0; j < 2; j++) {
    qd2[j] = (qa1[2 * j] - qa1[2 * j + 1]) * c;
    qa2[j] = (qa1[2 * j] + qa1[2 * j + 1]) * c;
    vd2[j] = (va1[2 * j] - va1[2 * j + 1]) * c;
    va2[j] = (va1[2 * j] + va1[2 * j + 1]) * c;
  }
  const float qd3 = (qa2[0] - qa2[1]) * c, qa3 = (qa2[0] + qa2[1]) * c;
  const float vd3 = (va2[0] - va2[1]) * c, va3 = (va2[0] + va2[1]) * c;

  const int wb = h * 192 + dh;
  const float wq0 = wq[wb], wq1 = wq[wb + 64], wq2 = wq[wb + 128];
  const float wv0 = wv[wb], wv1 = wv[wb + 64], wv2 = wv[wb + 128];

  const float pa = (qa3 * wq0) * (va3 * wv0);
  const float pd3 = (qd3 * wq1) * (vd3 * wv1);
  float pd2[2], pd1[4];
#pragma unroll
  for (int j = 0; j < 2; j++) pd2[j] = (qd2[j] * wq2) * (vd2[j] * wv2);
#pragma unroll
  for (int i = 0; i < 4; i++) pd1[i] = qd1[i] * vd1[i];

  float s2[2], s1[4], a8[8];
  s2[0] = (pa + pd3) * c;
  s2[1] = (pa - pd3) * c;
#pragma unroll
  for (int j = 0; j < 2; j++) {
    s1[2 * j] = (s2[j] + pd2[j]) * c;
    s1[2 * j + 1] = (s2[j] - pd2[j]) * c;
  }
#pragma unroll
  for (int i = 0; i < 4; i++) {
    a8[2 * i] = (s1[i] + pd1[i]) * c;
    a8[2 * i + 1] = (s1[i] - pd1[i]) * c;
  }
#pragma unroll
  for (int i = 0; i < 8; i++) out[(m0 + i) * 1024 + d] = (f16)a8[i];
}

// ---------------- launch ----------------
extern "C" void kernel_launch(void* const* d_in, const int* in_sizes, int n_in,
                              void* d_out, int out_size, void* d_ws, size_t ws_size,
                              hipStream_t stream) {
  (void)in_sizes; (void)n_in; (void)out_size; (void)ws_size;
  const float* query = (const float*)d_in[0];
  const float* W_qkv = (const float*)d_in[1];
  const float* b_qkv = (const float*)d_in[2];
  const float* W_out = (const float*)d_in[3];
  const float* b_out = (const float*)d_in[4];
  const float* wq = (const float*)d_in[5];
  const float* wv = (const float*)d_in[6];
  float* out = (float*)d_out;

  // workspace layout
  char* ws = (char*)d_ws;
  f16* qf16 = (f16*)ws;                                // 67,108,864 B (reused as a_f16)
  f16* Wqv = (f16*)(ws + 67108864);                    //  4,194,304 B
  float* bqv = (float*)(ws + 67108864 + 4194304);      //      8,192 B
  f16* Wout = (f16*)(ws + 67108864 + 4194304 + 8192);  //  2,097,152 B
  f16* qv = (f16*)d_out;  // qv intermediate lives in d_out (exactly out bytes)
  f16* a_f16 = qf16;      // alias: qf16 dead after GEMM1

  // 1. query -> f16
  cvt_f32_f16_k<<<dim3(8388608 / 256), dim3(256), 0, stream>>>(query, qf16, 8388608);
  // 2. pack W_qv + bias
  pack_wqv_k<<<dim3(2048), dim3(256), 0, stream>>>(W_qkv, b_qkv, Wqv, bqv);
  // 3. W_out -> f16
  cvt_f32_f16_k<<<dim3(262144 / 256), dim3(256), 0, stream>>>(W_out, Wout, 262144);
  // 4. GEMM1: qv[32768,2048] = query_f16 * Wqv^T + bqv   (grid 8*128 = 1024 blocks)
  gemm256_k<f16><<<dim3((2048 / 256) * (32768 / 256)), dim3(512), 0, stream>>>(
      qf16, Wqv, bqv, qv, 32768, 2048, 1024, 2048 / 256);
  // 5. fused wavelet middle: a[32768,1024] f16
  dwt_middle_k<<<dim3(16384), dim3(256), 0, stream>>>(qv, wq, wv, a_f16);
  // 6. GEMM2: out = a * Wout^T + b_out (fp32)   (grid 4*128 = 512 blocks)
  gemm256_k<float><<<dim3((1024 / 256) * (32768 / 256)), dim3(512), 0, stream>>>(
      a_f16, Wout, b_out, out, 32768, 1024, 1024, 1024 / 256);
}